// Round 2
// baseline (1350.941 us; speedup 1.0000x reference)
//
#include <hip/hip_runtime.h>
#include <math.h>

// Cosine top-10: query [1,256] f32, docs [1e6,256] f32.
// Memory-bound stream: 1.024 GB docs read once -> ~163 us floor @6.3 TB/s.
// R1: + depth-1 software prefetch so the 6-step shuffle reduce overlaps the
//     next doc's HBM access (keep a load in flight per wave ~always).

constexpr int   D              = 256;
constexpr float EPSV           = 1e-12f;
constexpr int   BLOCKS1        = 1024;   // 4 blocks/CU
constexpr int   TPB1           = 256;    // 4 waves/block -> 16 waves/CU
constexpr int   WAVES_PER_BLK  = TPB1 / 64;
constexpr int   NWAVES         = BLOCKS1 * WAVES_PER_BLK;   // 4096
constexpr int   NCAND          = NWAVES * 10;               // 40960 -> 320 KB ws

// ---------------- Kernel 1: stream docs, per-wave top-10 ----------------
__global__ __launch_bounds__(TPB1) void cosine_topk_partial(
    const float* __restrict__ query, const float* __restrict__ docs,
    int ndocs, float* __restrict__ cand_val, int* __restrict__ cand_idx)
{
    const int lane = threadIdx.x & 63;
    const int wid  = blockIdx.x * WAVES_PER_BLK + (threadIdx.x >> 6);

    // Query fragment: lane i owns elements [4i..4i+3]. Wave covers all 256.
    const float4 q = *reinterpret_cast<const float4*>(query + (lane << 2));

    // l2_q = sqrt(sum(max(q^2, EPS))) — once per wave.
    float qss = fmaxf(q.x * q.x, EPSV) + fmaxf(q.y * q.y, EPSV)
              + fmaxf(q.z * q.z, EPSV) + fmaxf(q.w * q.w, EPSV);
    #pragma unroll
    for (int off = 1; off < 64; off <<= 1) qss += __shfl_xor(qss, off, 64);
    const float l2q = sqrtf(qss);

    // Per-wave top-10, sorted descending. All lanes hold identical state
    // (xor-reduce broadcasts sums), so all branches are wave-uniform.
    float v[10]; int id[10];
    #pragma unroll
    for (int j = 0; j < 10; ++j) { v[j] = -INFINITY; id[j] = 0x7fffffff; }

    const float* lanep = docs + (lane << 2);   // lane's 16B slot within a doc

    // Prefetch doc 0 (wave-uniform predicate; grid covers ndocs >= NWAVES).
    float4 dv = make_float4(0.f, 0.f, 0.f, 0.f);
    if (wid < ndocs)
        dv = *reinterpret_cast<const float4*>(lanep + (size_t)wid * D);

    for (int doc = wid; doc < ndocs; doc += NWAVES) {
        // Issue next doc's load BEFORE the serial reduce chain (latency hide).
        const int nxt = doc + NWAVES;
        float4 nv = make_float4(0.f, 0.f, 0.f, 0.f);
        if (nxt < ndocs)
            nv = *reinterpret_cast<const float4*>(lanep + (size_t)nxt * D);

        float dot = q.x * dv.x + q.y * dv.y + q.z * dv.z + q.w * dv.w;
        float ss  = fmaxf(dv.x * dv.x, EPSV) + fmaxf(dv.y * dv.y, EPSV)
                  + fmaxf(dv.z * dv.z, EPSV) + fmaxf(dv.w * dv.w, EPSV);
        #pragma unroll
        for (int off = 1; off < 64; off <<= 1) {
            dot += __shfl_xor(dot, off, 64);
            ss  += __shfl_xor(ss,  off, 64);
        }
        const float c = dot / (l2q * sqrtf(ss));

        // Rare (≈30/wave over the whole loop): unrolled sorted insert.
        // Strict '>' keeps equal values behind earlier (lower-index) entries.
        if (c > v[9]) {
            #pragma unroll
            for (int j = 9; j >= 1; --j) {
                const bool shift = c > v[j - 1];
                const bool ins   = c > v[j];
                v[j]  = shift ? v[j - 1]  : (ins ? c   : v[j]);
                id[j] = shift ? id[j - 1] : (ins ? doc : id[j]);
            }
            if (c > v[0]) { v[0] = c; id[0] = doc; }
        }

        dv = nv;
    }

    if (lane == 0) {
        #pragma unroll
        for (int j = 0; j < 10; ++j) {
            cand_val[wid * 10 + j] = v[j];
            cand_idx[wid * 10 + j] = id[j];
        }
    }
}

// ---------------- Kernel 2: merge 40960 candidates -> global top-10 ----------------
__device__ __forceinline__ bool beats(float av, int ai, float bv, int bi) {
    return (av > bv) || (av == bv && ai < bi);   // stable: lower index wins ties
}

__global__ __launch_bounds__(1024) void topk_merge(
    const float* __restrict__ cand_val, const int* __restrict__ cand_idx,
    float* __restrict__ out)
{
    __shared__ float sval[16];
    __shared__ int   sidx[16];
    __shared__ float wval;
    __shared__ int   widx;

    const int tid  = threadIdx.x;
    const int lane = tid & 63;
    const int wv   = tid >> 6;

    float v[10]; int id[10];
    #pragma unroll
    for (int j = 0; j < 10; ++j) { v[j] = -INFINITY; id[j] = 0x7fffffff; }

    // Per-thread top-10 over its strided slice (40 candidates/thread).
    for (int c = tid; c < NCAND; c += 1024) {
        const float cv = cand_val[c];
        const int   ci = cand_idx[c];
        if (beats(cv, ci, v[9], id[9])) {
            #pragma unroll
            for (int j = 9; j >= 1; --j) {
                const bool shift = beats(cv, ci, v[j - 1], id[j - 1]);
                const bool ins   = beats(cv, ci, v[j],     id[j]);
                v[j]  = shift ? v[j - 1]  : (ins ? cv : v[j]);
                id[j] = shift ? id[j - 1] : (ins ? ci : id[j]);
            }
            if (beats(cv, ci, v[0], id[0])) { v[0] = cv; id[0] = ci; }
        }
    }

    // 10 rounds: block-wide argmax of heads, winner pops (static shift).
    for (int r = 0; r < 10; ++r) {
        float hv = v[0]; int hi = id[0];
        #pragma unroll
        for (int off = 1; off < 64; off <<= 1) {
            const float ov = __shfl_xor(hv, off, 64);
            const int   oi = __shfl_xor(hi, off, 64);
            if (beats(ov, oi, hv, hi)) { hv = ov; hi = oi; }
        }
        if (lane == 0) { sval[wv] = hv; sidx[wv] = hi; }
        __syncthreads();
        if (wv == 0) {
            float gv = (lane < 16) ? sval[lane] : -INFINITY;
            int   gi = (lane < 16) ? sidx[lane] : 0x7fffffff;
            #pragma unroll
            for (int off = 1; off < 16; off <<= 1) {
                const float ov = __shfl_xor(gv, off, 64);
                const int   oi = __shfl_xor(gi, off, 64);
                if (beats(ov, oi, gv, gi)) { gv = ov; gi = oi; }
            }
            if (lane == 0) {
                wval = gv; widx = gi;
                out[r]      = gv;           // top_k values
                out[10 + r] = (float)gi;    // indices (f32 under tuple concat)
            }
        }
        __syncthreads();
        // Owner (unique doc index) pops its head via static shift.
        if (id[0] == widx && v[0] == wval) {
            #pragma unroll
            for (int j = 0; j < 9; ++j) { v[j] = v[j + 1]; id[j] = id[j + 1]; }
            v[9] = -INFINITY; id[9] = 0x7fffffff;
        }
        __syncthreads();
    }
}

extern "C" void kernel_launch(void* const* d_in, const int* in_sizes, int n_in,
                              void* d_out, int out_size, void* d_ws, size_t ws_size,
                              hipStream_t stream) {
    const float* query = (const float*)d_in[0];
    const float* docs  = (const float*)d_in[1];
    const int    ndocs = in_sizes[1] / D;

    float* cand_val = (float*)d_ws;
    int*   cand_idx = (int*)((char*)d_ws + (size_t)NCAND * sizeof(float));

    cosine_topk_partial<<<BLOCKS1, TPB1, 0, stream>>>(
        query, docs, ndocs, cand_val, cand_idx);
    topk_merge<<<1, 1024, 0, stream>>>(cand_val, cand_idx, (float*)d_out);
}